// Round 11
// baseline (894.813 us; speedup 1.0000x reference)
//
#include <hip/hip_runtime.h>
#include <stdint.h>

// Bloom filter, 2^27 bits, 7 hashes = 7 CONSECUTIVE bits starting at
//   p = ((uint32)v * 2654435761u) & (2^27 - 1)   (wraps mod 2^27)
// Harness dtypes: integer inputs -> int32; bool output -> int32 (0/1).
//
// R10 post-mortem: scatter and build were BOTH ~80 us; shared disease =
// 1-2 blocks/CU (huge LDS) + sparse lanes, i.e. latency-starved. This round:
//  - place: 2048 blocks, 21 KB LDS (~7 blocks/CU), single pass, 64
//    super-buckets (2^21 bits), CAP-80 LDS cells (overflow P ~ 1e-10),
//    per-cell global-cursor flush of contiguous runs. Deterministic: exact
//    capacity + idempotent OR; cursor races only permute within a region.
//  - build: 512 blocks = (super, octant); dense coalesced scan of the
//    super's contiguous list, register filter for the 2^18-bit region.
// Query (H pre-filter) unchanged: H[m]=AND of fine bits[4m..4m+3] (4 MiB,
// L2-resident) kills ~87% of queries with an L2 hit.

#define NUM_BITS_LOG2 27
#define NUM_BITS (1u << NUM_BITS_LOG2)
#define BIT_MASK (NUM_BITS - 1u)
#define NUM_WORDS (NUM_BITS >> 6)             // 2^21 u64 words = 16 MiB
#define WORD_MASK (NUM_WORDS - 1u)
#define PRIME 2654435761u

#define NSUPER 64                             // super-bucket = 2^21 bits
#define SUP_SHIFT 21
#define NREGION 512                           // build region = 2^18 bits
#define REG_SHIFT 18
#define REGION_WORDS (1u << (REG_SHIFT - 6))  // 4096 u64 = 32 KiB
#define H_WORDS_PER_REGION (REGION_WORDS / 4) // 1024 u64 H-words per region
#define BLOCKS_P 2048
#define CAPP 80u                              // per-(block,super) cell; E=33.3
#define SUP_PAD 76800u                        // u32 per super; E=68.2k, +33 sigma

typedef int vint4 __attribute__((ext_vector_type(4)));
typedef unsigned long long vull2 __attribute__((ext_vector_type(2)));

// ---------------- workspace layout (bytes) ----------------
// [0, 16777216)            bits    u64 x 2^21   (16 MiB)
// [16777216, 20971520)     H       u64 x 2^19   (4 MiB)
// [20971520, 40632320)     lists2  u32 x 64*76800  (super-bucket-major, padded)
// [40632320, 40632576)     gcur    u32 x 64 (+pad)
#define WS_REQUIRED 40632576ull

__global__ void init_gcur_kernel(uint32_t* gcur) {
    int t = threadIdx.x;
    if (t < NSUPER) gcur[t] = (uint32_t)t * SUP_PAD;   // absolute base index
}

// ---------- place: single-pass super-bucket binning, high occupancy ----------
__global__ __launch_bounds__(256) void place_kernel(
    const int* __restrict__ vals, int n,
    uint32_t* __restrict__ lists2, uint32_t* __restrict__ gcur)
{
    __shared__ uint32_t cnt[NSUPER];
    __shared__ uint32_t buf[NSUPER * CAPP];   // 20.5 KB
    const int blk = blockIdx.x, tid = threadIdx.x;
    if (tid < NSUPER) cnt[tid] = 0;
    __syncthreads();

    const int n4 = n >> 2;
    for (int g = blk * 256 + tid; g < n4; g += BLOCKS_P * 256) {
        vint4 v = __builtin_nontemporal_load((const vint4*)vals + g);
        #pragma unroll
        for (int j = 0; j < 4; ++j) {
            uint32_t p = ((uint32_t)v[j] * PRIME) & BIT_MASK;
            uint32_t s1 = p >> SUP_SHIFT;
            uint32_t c1 = atomicAdd(&cnt[s1], 1u);
            if (c1 < CAPP) buf[s1 * CAPP + c1] = p;   // clamp unreachable (~1e-10)
            uint32_t q = (p + 6u) & BIT_MASK;
            uint32_t s2 = q >> SUP_SHIFT;
            if (s2 != s1) {                            // window crosses super boundary
                uint32_t c2 = atomicAdd(&cnt[s2], 1u);
                if (c2 < CAPP) buf[s2 * CAPP + c2] = p;
            }
        }
    }
    for (int i = (n4 << 2) + blk * 256 + tid; i < n; i += BLOCKS_P * 256) {
        uint32_t p = ((uint32_t)vals[i] * PRIME) & BIT_MASK;
        uint32_t s1 = p >> SUP_SHIFT;
        uint32_t c1 = atomicAdd(&cnt[s1], 1u);
        if (c1 < CAPP) buf[s1 * CAPP + c1] = p;
        uint32_t q = (p + 6u) & BIT_MASK;
        uint32_t s2 = q >> SUP_SHIFT;
        if (s2 != s1) {
            uint32_t c2 = atomicAdd(&cnt[s2], 1u);
            if (c2 < CAPP) buf[s2 * CAPP + c2] = p;
        }
    }
    __syncthreads();

    // flush: each wave handles 16 cells; one cursor atomic per cell,
    // then a contiguous ~132 B run copy (coalesced-ish, fire-and-forget)
    const uint32_t wave = tid >> 6, lane = tid & 63u;
    for (uint32_t s = wave * 16u; s < wave * 16u + 16u; ++s) {
        uint32_t c = min(cnt[s], CAPP);
        uint32_t base = 0;
        if (lane == 0 && c > 0) base = atomicAdd(&gcur[s], c);
        base = __shfl(base, 0);
        for (uint32_t k = lane; k < c; k += 64u)
            lists2[base + k] = buf[s * CAPP + k];
    }
}

// ---------- build: dense scan of super list, register filter per region ----------
__device__ __forceinline__ void set_window(unsigned long long* bm, uint32_t p, uint32_t r) {
    int d = (int)((p - (r << REG_SHIFT)) & BIT_MASK);
    if (d >= (1 << 26)) d -= (1 << 27);                 // entry from prev region / wrap
    if (d < -6 || d >= (1 << REG_SHIFT)) return;        // safety guard
    if (d < 0) {
        atomicOr(&bm[0], 0x7Full >> (uint32_t)(-d));
    } else {
        uint32_t w = (uint32_t)d >> 6, s = (uint32_t)d & 63u;
        atomicOr(&bm[w], 0x7Full << s);
        if (s > 57u) atomicOr(&bm[w + 1], 0x7Full >> (64u - s));  // slack word absorbs
    }
}

// 16 nibble-AND bits of one u64 fine word, compacted to low 16 bits
__device__ __forceinline__ unsigned long long nib16(unsigned long long a) {
    unsigned long long t = a & (a >> 1);
    unsigned long long u = t & (t >> 2);                // bit 4k = AND of bits 4k..4k+3
    u &= 0x1111111111111111ull;
    u |= u >> 3;  u &= 0x0303030303030303ull;
    u |= u >> 6;  u &= 0x000F000F000F000Full;
    u |= u >> 12; u &= 0x000000FF000000FFull;
    u |= u >> 24; return u & 0xFFFFull;
}

__global__ __launch_bounds__(256) void build_bitmap_kernel(
    const uint32_t* __restrict__ lists2, const uint32_t* __restrict__ gcur,
    unsigned long long* __restrict__ bits, unsigned long long* __restrict__ H)
{
    __shared__ unsigned long long bm[REGION_WORDS + 1];
    const uint32_t r = blockIdx.x;                // region 0..511
    const uint32_t s = r >> 3;                    // super 0..63
    const uint32_t tid = threadIdx.x;
    for (uint32_t i = tid; i < REGION_WORDS + 1; i += 256) bm[i] = 0ull;
    __syncthreads();

    const uint32_t base = s * SUP_PAD;
    uint32_t c = gcur[s] - base;                  // exact entry count for super s
    c = min(c, SUP_PAD);
    for (uint32_t k = tid; k < c; k += 256) {     // dense coalesced, full lanes
        uint32_t p = lists2[base + k];
        uint32_t q = (p + 6u) & BIT_MASK;
        if ((p >> REG_SHIFT) == r || (q >> REG_SHIFT) == r)
            set_window(bm, p, r);
    }
    __syncthreads();
    const uint32_t out_base = r * REGION_WORDS;
    for (uint32_t i = tid; i < REGION_WORDS; i += 256)
        __builtin_nontemporal_store(bm[i], &bits[out_base + i]);
    const uint32_t h_base = r * H_WORDS_PER_REGION;
    for (uint32_t i = tid; i < H_WORDS_PER_REGION; i += 256) {
        unsigned long long hw = nib16(bm[i * 4])
                              | (nib16(bm[i * 4 + 1]) << 16)
                              | (nib16(bm[i * 4 + 2]) << 32)
                              | (nib16(bm[i * 4 + 3]) << 48);
        H[h_base + i] = hw;                 // temporal store: H wants to live in L2
    }
}

// ---------- query: H pre-filter (L2-resident), fine bitmap only on pass ----------
__device__ __forceinline__ int query_one_branchy(uint32_t v,
                                                 const unsigned long long* __restrict__ bits) {
    uint32_t p = (v * PRIME) & BIT_MASK;
    uint32_t w = p >> 6, s = p & 63u;
    unsigned long long lo = bits[w];
    unsigned long long win;
    if (s <= 57u) win = lo >> s;
    else win = (lo >> s) | (bits[(w + 1u) & WORD_MASK] << (64u - s));
    return ((win & 0x7Full) == 0x7Full) ? 1 : 0;
}

__global__ __launch_bounds__(256) void query_kernelH(
    const int* __restrict__ vals, int n,
    const unsigned long long* __restrict__ bits,
    const uint32_t* __restrict__ H32, int* __restrict__ out)
{
    int t = blockIdx.x * 256 + threadIdx.x;
    int base = t * 8;
    if (base + 7 < n) {
        vint4 v0 = __builtin_nontemporal_load((const vint4*)(vals + base));
        vint4 v1 = __builtin_nontemporal_load((const vint4*)(vals + base + 4));
        uint32_t p[8], pass[8];
        #pragma unroll
        for (int j = 0; j < 4; ++j) {
            p[j]     = ((uint32_t)v0[j] * PRIME) & BIT_MASK;
            p[j + 4] = ((uint32_t)v1[j] * PRIME) & BIT_MASK;
        }
        #pragma unroll
        for (int j = 0; j < 8; ++j) {           // 8 independent L2-hit H probes
            uint32_t m = ((p[j] + 3u) & BIT_MASK) >> 2;
            pass[j] = (H32[m >> 5] >> (m & 31u)) & 1u;
        }
        unsigned long long lo[8], hi[8];
        uint32_t w[8], s[8];
        #pragma unroll
        for (int j = 0; j < 8; ++j) {           // masked fine gathers (~13% lanes)
            w[j] = p[j] >> 6; s[j] = p[j] & 63u;
            lo[j] = 0ull; hi[j] = 0ull;
            if (pass[j]) lo[j] = __builtin_nontemporal_load(&bits[w[j]]);
        }
        #pragma unroll
        for (int j = 0; j < 8; ++j) {           // masked hi gathers (~1.1% lanes)
            if (pass[j] && s[j] > 57u)
                hi[j] = __builtin_nontemporal_load(&bits[(w[j] + 1u) & WORD_MASK]);
        }
        vint4 r0, r1;
        #pragma unroll
        for (int j = 0; j < 8; ++j) {
            unsigned long long win = (lo[j] >> s[j]) | ((hi[j] << 1) << (63u - s[j]));
            int r = ((win & 0x7Full) == 0x7Full) ? 1 : 0;
            if (j < 4) r0[j] = r; else r1[j - 4] = r;
        }
        __builtin_nontemporal_store(r0, (vint4*)(out + base));
        __builtin_nontemporal_store(r1, (vint4*)(out + base + 4));
    } else {
        for (int j = base; j < n; ++j)
            out[j] = query_one_branchy((uint32_t)vals[j], bits);
    }
}

// ---------- fallback path (small ws): global-atomic insert + plain query ----------
__global__ void zero_bits_kernel(vull2* __restrict__ bits, int n2) {
    int i = blockIdx.x * blockDim.x + threadIdx.x;
    if (i < n2) { vull2 z = {0ull, 0ull}; __builtin_nontemporal_store(z, &bits[i]); }
}

__device__ __forceinline__ void insert_one_atomic(uint32_t v,
                                                  unsigned long long* __restrict__ bits) {
    uint32_t p = (v * PRIME) & BIT_MASK;
    uint32_t w = p >> 6, s = p & 63u;
    atomicOr(bits + w, 0x7Full << s);
    if (s > 57u) atomicOr(bits + ((w + 1u) & WORD_MASK), 0x7Full >> (64u - s));
}

__global__ void insert_atomic_kernel(const int* __restrict__ vals, int n,
                                     unsigned long long* __restrict__ bits) {
    int i = blockIdx.x * blockDim.x + threadIdx.x;
    int base = i * 4;
    if (base + 3 < n) {
        vint4 v = __builtin_nontemporal_load((const vint4*)(vals + base));
        insert_one_atomic((uint32_t)v.x, bits);
        insert_one_atomic((uint32_t)v.y, bits);
        insert_one_atomic((uint32_t)v.z, bits);
        insert_one_atomic((uint32_t)v.w, bits);
    } else {
        for (int j = base; j < n; ++j) insert_one_atomic((uint32_t)vals[j], bits);
    }
}

__global__ __launch_bounds__(256) void query_kernel8(
    const int* __restrict__ vals, int n,
    const unsigned long long* __restrict__ bits, int* __restrict__ out)
{
    int t = blockIdx.x * 256 + threadIdx.x;
    int base = t * 8;
    if (base + 7 < n) {
        vint4 v0 = __builtin_nontemporal_load((const vint4*)(vals + base));
        vint4 v1 = __builtin_nontemporal_load((const vint4*)(vals + base + 4));
        vint4 r0, r1;
        #pragma unroll
        for (int j = 0; j < 8; ++j) {
            uint32_t v = (uint32_t)(j < 4 ? v0[j] : v1[j - 4]);
            int r = query_one_branchy(v, bits);
            if (j < 4) r0[j] = r; else r1[j - 4] = r;
        }
        __builtin_nontemporal_store(r0, (vint4*)(out + base));
        __builtin_nontemporal_store(r1, (vint4*)(out + base + 4));
    } else {
        for (int j = base; j < n; ++j)
            out[j] = query_one_branchy((uint32_t)vals[j], bits);
    }
}

extern "C" void kernel_launch(void* const* d_in, const int* in_sizes, int n_in,
                              void* d_out, int out_size, void* d_ws, size_t ws_size,
                              hipStream_t stream) {
    const int* add_values   = (const int*)d_in[0];
    const int* query_values = (const int*)d_in[1];
    const int n_add   = in_sizes[0];   // 4,000,000
    const int n_query = in_sizes[1];   // 8,000,000
    int* out = (int*)d_out;

    uint8_t* ws = (uint8_t*)d_ws;
    unsigned long long* bits = (unsigned long long*)ws;
    unsigned long long* H    = (unsigned long long*)(ws + 16777216);
    uint32_t* lists2 = (uint32_t*)(ws + 20971520);
    uint32_t* gcur   = (uint32_t*)(ws + 40632320);

    if (ws_size >= WS_REQUIRED) {
        init_gcur_kernel<<<1, 64, 0, stream>>>(gcur);
        place_kernel<<<BLOCKS_P, 256, 0, stream>>>(
            add_values, n_add, lists2, gcur);
        build_bitmap_kernel<<<NREGION, 256, 0, stream>>>(
            lists2, gcur, bits, H);
        const int threads = (n_query + 7) / 8;
        query_kernelH<<<(threads + 255) / 256, 256, 0, stream>>>(
            query_values, n_query, bits, (const uint32_t*)H, out);
    } else {
        const int n2 = NUM_WORDS / 2;
        zero_bits_kernel<<<(n2 + 255) / 256, 256, 0, stream>>>((vull2*)bits, n2);
        const int threads4 = (n_add + 3) / 4;
        insert_atomic_kernel<<<(threads4 + 255) / 256, 256, 0, stream>>>(
            add_values, n_add, bits);
        const int threads = (n_query + 7) / 8;
        query_kernel8<<<(threads + 255) / 256, 256, 0, stream>>>(
            query_values, n_query, bits, out);
    }
}

// Round 12
// 246.099 us; speedup vs baseline: 3.6360x; 3.6360x over previous
//
#include <hip/hip_runtime.h>
#include <stdint.h>

// Bloom filter, 2^27 bits, 7 hashes = 7 CONSECUTIVE bits starting at
//   p = ((uint32)v * 2654435761u) & (2^27 - 1)   (wraps mod 2^27)
// Harness dtypes: integer inputs -> int32; bool output -> int32 (0/1).
//
// R11 post-mortem: 64-bin LDS-atomic binning exploded (SQ_LDS_BANK_CONFLICT
// 739k, 618 us) — LDS-atomic same-address/same-bank contention scales
// inversely with bin count; occupancy is irrelevant (per-CU LDS pipe wall).
// This round: revert insert path to R9 (known 224 us, deterministic exact
// two-pass 512-bin scatter + wave-cooperative build), and double query MLP:
// 16 queries/thread (16 H probes in flight before any fine gather).
// Query H pre-filter: H[m]=AND of fine bits[4m..4m+3] (4 MiB, L2-resident)
// kills ~87% of queries with an L2 hit; fine loads NT to protect H in L2.

#define NUM_BITS_LOG2 27
#define NUM_BITS (1u << NUM_BITS_LOG2)
#define BIT_MASK (NUM_BITS - 1u)
#define NUM_WORDS (NUM_BITS >> 6)             // 2^21 u64 words = 16 MiB
#define WORD_MASK (NUM_WORDS - 1u)
#define PRIME 2654435761u

#define NBUCKETS 512
#define BKT_SHIFT (NUM_BITS_LOG2 - 9)         // 18: region = 2^18 bits
#define REGION_WORDS (1u << (BKT_SHIFT - 6))  // 4096 u64 = 32 KiB
#define H_WORDS_PER_REGION (REGION_WORDS / 4) // 1024 u64 H-words per region
#define BLOCKS_A 256
#define BLOCK_SEG 16896u                      // per-block entry segment (u32)

typedef int vint4 __attribute__((ext_vector_type(4)));
typedef unsigned long long vull2 __attribute__((ext_vector_type(2)));

// ---------------- workspace layout (bytes) ----------------
// [0, 16777216)            bits   u64 x 2^21   (16 MiB)
// [16777216, 20971520)     H      u64 x 2^19   (4 MiB)
// [20971520, 38273024)     lists  u32 x 256*16896
// [38273024, 38798336)     off_t  u32 x 513*256  (off_t[bucket*256+blk])
#define WS_REQUIRED 38798336ull

// ---------- phase A: exact two-pass bucket scatter (no global atomics) ----------
__global__ __launch_bounds__(256) void scatter_add_kernel(
    const int* __restrict__ vals, int n,
    uint32_t* __restrict__ lists, uint32_t* __restrict__ off_t)
{
    __shared__ uint32_t cnt[NBUCKETS];
    __shared__ uint32_t scan[NBUCKETS];
    __shared__ uint32_t off[NBUCKETS + 1];
    __shared__ uint32_t cur[NBUCKETS];
    const int blk = blockIdx.x, tid = threadIdx.x;
    for (int i = tid; i < NBUCKETS; i += 256) cnt[i] = 0;
    __syncthreads();

    const int n4 = n >> 2;
    // ---- pass 1: count (traversal identical to pass 2) ----
    for (int g = blk * 256 + tid; g < n4; g += BLOCKS_A * 256) {
        vint4 v = __builtin_nontemporal_load((const vint4*)vals + g);
        #pragma unroll
        for (int j = 0; j < 4; ++j) {
            uint32_t p = ((uint32_t)v[j] * PRIME) & BIT_MASK;
            uint32_t b1 = p >> BKT_SHIFT;
            atomicAdd(&cnt[b1], 1u);
            uint32_t b2 = ((p + 6u) & BIT_MASK) >> BKT_SHIFT;
            if (b2 != b1) atomicAdd(&cnt[b2], 1u);
        }
    }
    for (int i = (n4 << 2) + blk * 256 + tid; i < n; i += BLOCKS_A * 256) {
        uint32_t p = ((uint32_t)vals[i] * PRIME) & BIT_MASK;
        uint32_t b1 = p >> BKT_SHIFT;
        atomicAdd(&cnt[b1], 1u);
        uint32_t b2 = ((p + 6u) & BIT_MASK) >> BKT_SHIFT;
        if (b2 != b1) atomicAdd(&cnt[b2], 1u);
    }
    __syncthreads();

    // ---- Hillis-Steele inclusive scan over 512 bins (each thread owns 2) ----
    scan[tid] = cnt[tid];
    scan[tid + 256] = cnt[tid + 256];
    __syncthreads();
    for (uint32_t d = 1; d < NBUCKETS; d <<= 1) {
        uint32_t i0 = tid, i1 = tid + 256;
        uint32_t v0 = (i0 >= d) ? scan[i0 - d] : 0u;
        uint32_t v1 = (i1 >= d) ? scan[i1 - d] : 0u;
        __syncthreads();
        scan[i0] += v0;
        scan[i1] += v1;
        __syncthreads();
    }
    if (tid == 0) off[0] = 0;
    off[tid + 1] = scan[tid];
    off[tid + 257] = scan[tid + 256];
    __syncthreads();
    cur[tid] = off[tid];
    cur[tid + 256] = off[tid + 256];
    __syncthreads();

    // ---- pass 2: exact scatter ----
    const uint32_t seg = (uint32_t)blk * BLOCK_SEG;
    for (int g = blk * 256 + tid; g < n4; g += BLOCKS_A * 256) {
        vint4 v = __builtin_nontemporal_load((const vint4*)vals + g);
        #pragma unroll
        for (int j = 0; j < 4; ++j) {
            uint32_t p = ((uint32_t)v[j] * PRIME) & BIT_MASK;
            uint32_t b1 = p >> BKT_SHIFT;
            uint32_t s = atomicAdd(&cur[b1], 1u);
            if (s < BLOCK_SEG) lists[seg + s] = p;        // clamp: unreachable for this input
            uint32_t b2 = ((p + 6u) & BIT_MASK) >> BKT_SHIFT;
            if (b2 != b1) {
                uint32_t s2 = atomicAdd(&cur[b2], 1u);
                if (s2 < BLOCK_SEG) lists[seg + s2] = p;
            }
        }
    }
    for (int i = (n4 << 2) + blk * 256 + tid; i < n; i += BLOCKS_A * 256) {
        uint32_t p = ((uint32_t)vals[i] * PRIME) & BIT_MASK;
        uint32_t b1 = p >> BKT_SHIFT;
        uint32_t s = atomicAdd(&cur[b1], 1u);
        if (s < BLOCK_SEG) lists[seg + s] = p;
        uint32_t b2 = ((p + 6u) & BIT_MASK) >> BKT_SHIFT;
        if (b2 != b1) {
            uint32_t s2 = atomicAdd(&cur[b2], 1u);
            if (s2 < BLOCK_SEG) lists[seg + s2] = p;
        }
    }
    __syncthreads();
    // off_t transposed: build block b reads off_t[b*256 + tid] coalesced
    for (int i = tid; i < NBUCKETS + 1; i += 256)
        off_t[(uint32_t)i * BLOCKS_A + blk] = off[i];
}

// ---------- phase B: build region bitmap in LDS, emit bits + H ----------
__device__ __forceinline__ void set_window(unsigned long long* bm, uint32_t p, uint32_t b) {
    int d = (int)((p - (b << BKT_SHIFT)) & BIT_MASK);
    if (d >= (1 << 26)) d -= (1 << 27);                 // dup from prev region / wrap
    if (d < -6 || d >= (1 << BKT_SHIFT)) return;        // safety guard
    if (d < 0) {
        atomicOr(&bm[0], 0x7Full >> (uint32_t)(-d));
    } else {
        uint32_t w = (uint32_t)d >> 6, s = (uint32_t)d & 63u;
        atomicOr(&bm[w], 0x7Full << s);
        if (s > 57u) atomicOr(&bm[w + 1], 0x7Full >> (64u - s));  // slack word absorbs
    }
}

// 16 nibble-AND bits of one u64 fine word, compacted to low 16 bits
__device__ __forceinline__ unsigned long long nib16(unsigned long long a) {
    unsigned long long t = a & (a >> 1);
    unsigned long long u = t & (t >> 2);                // bit 4k = AND of bits 4k..4k+3
    u &= 0x1111111111111111ull;
    u |= u >> 3;  u &= 0x0303030303030303ull;
    u |= u >> 6;  u &= 0x000F000F000F000Full;
    u |= u >> 12; u &= 0x000000FF000000FFull;
    u |= u >> 24; return u & 0xFFFFull;
}

__global__ __launch_bounds__(256) void build_bitmap_kernel(
    const uint32_t* __restrict__ lists, const uint32_t* __restrict__ off_t,
    unsigned long long* __restrict__ bits, unsigned long long* __restrict__ H)
{
    __shared__ unsigned long long bm[REGION_WORDS + 1];
    __shared__ uint32_t o0s[BLOCKS_A];
    __shared__ uint32_t c_s[BLOCKS_A];
    const uint32_t b = blockIdx.x, tid = threadIdx.x;
    for (uint32_t i = tid; i < REGION_WORDS + 1; i += 256) bm[i] = 0ull;
    for (uint32_t a = tid; a < BLOCKS_A; a += 256) {               // coalesced
        uint32_t o0 = min(off_t[b * BLOCKS_A + a], BLOCK_SEG);
        uint32_t o1 = min(off_t[(b + 1) * BLOCKS_A + a], BLOCK_SEG);
        o0s[a] = o0;
        c_s[a] = (o1 > o0) ? (o1 - o0) : 0u;
    }
    __syncthreads();

    // wave-cooperative: wave w walks source blocks w, w+4, ...; lanes coalesced
    const uint32_t wave = tid >> 6, lane = tid & 63u;
    for (uint32_t a = wave; a < BLOCKS_A; a += 4) {
        uint32_t c = c_s[a];
        uint32_t base = a * BLOCK_SEG + o0s[a];
        for (uint32_t k = lane; k < c; k += 64)
            set_window(bm, lists[base + k], b);
    }
    __syncthreads();
    const uint32_t out_base = b * REGION_WORDS;
    for (uint32_t i = tid; i < REGION_WORDS; i += 256)
        __builtin_nontemporal_store(bm[i], &bits[out_base + i]);
    const uint32_t h_base = b * H_WORDS_PER_REGION;
    for (uint32_t i = tid; i < H_WORDS_PER_REGION; i += 256) {
        unsigned long long hw = nib16(bm[i * 4])
                              | (nib16(bm[i * 4 + 1]) << 16)
                              | (nib16(bm[i * 4 + 2]) << 32)
                              | (nib16(bm[i * 4 + 3]) << 48);
        H[h_base + i] = hw;                 // temporal store: H wants to live in L2
    }
}

// ---------- query: 16/thread; H pre-filter, fine bitmap only on pass ----------
__device__ __forceinline__ int query_one_branchy(uint32_t v,
                                                 const unsigned long long* __restrict__ bits) {
    uint32_t p = (v * PRIME) & BIT_MASK;
    uint32_t w = p >> 6, s = p & 63u;
    unsigned long long lo = bits[w];
    unsigned long long win;
    if (s <= 57u) win = lo >> s;
    else win = (lo >> s) | (bits[(w + 1u) & WORD_MASK] << (64u - s));
    return ((win & 0x7Full) == 0x7Full) ? 1 : 0;
}

__global__ __launch_bounds__(256) void query_kernelH16(
    const int* __restrict__ vals, int n,
    const unsigned long long* __restrict__ bits,
    const uint32_t* __restrict__ H32, int* __restrict__ out)
{
    int t = blockIdx.x * 256 + threadIdx.x;
    int base = t * 16;
    if (base + 15 < n) {
        vint4 v0 = __builtin_nontemporal_load((const vint4*)(vals + base));
        vint4 v1 = __builtin_nontemporal_load((const vint4*)(vals + base + 4));
        vint4 v2 = __builtin_nontemporal_load((const vint4*)(vals + base + 8));
        vint4 v3 = __builtin_nontemporal_load((const vint4*)(vals + base + 12));
        uint32_t p[16], pass[16];
        #pragma unroll
        for (int j = 0; j < 4; ++j) {
            p[j]      = ((uint32_t)v0[j] * PRIME) & BIT_MASK;
            p[j + 4]  = ((uint32_t)v1[j] * PRIME) & BIT_MASK;
            p[j + 8]  = ((uint32_t)v2[j] * PRIME) & BIT_MASK;
            p[j + 12] = ((uint32_t)v3[j] * PRIME) & BIT_MASK;
        }
        #pragma unroll
        for (int j = 0; j < 16; ++j) {          // 16 independent L2-hit H probes
            uint32_t m = ((p[j] + 3u) & BIT_MASK) >> 2;
            pass[j] = (H32[m >> 5] >> (m & 31u)) & 1u;
        }
        unsigned long long lo[16], hi[16];
        uint32_t w[16], s[16];
        #pragma unroll
        for (int j = 0; j < 16; ++j) {          // masked fine gathers (~13% lanes)
            w[j] = p[j] >> 6; s[j] = p[j] & 63u;
            lo[j] = 0ull; hi[j] = 0ull;
            if (pass[j]) lo[j] = __builtin_nontemporal_load(&bits[w[j]]);
        }
        #pragma unroll
        for (int j = 0; j < 16; ++j) {          // masked hi gathers (~1.1% lanes)
            if (pass[j] && s[j] > 57u)
                hi[j] = __builtin_nontemporal_load(&bits[(w[j] + 1u) & WORD_MASK]);
        }
        vint4 r0, r1, r2, r3;
        #pragma unroll
        for (int j = 0; j < 16; ++j) {
            unsigned long long win = (lo[j] >> s[j]) | ((hi[j] << 1) << (63u - s[j]));
            int r = ((win & 0x7Full) == 0x7Full) ? 1 : 0;
            if (j < 4) r0[j] = r;
            else if (j < 8) r1[j - 4] = r;
            else if (j < 12) r2[j - 8] = r;
            else r3[j - 12] = r;
        }
        __builtin_nontemporal_store(r0, (vint4*)(out + base));
        __builtin_nontemporal_store(r1, (vint4*)(out + base + 4));
        __builtin_nontemporal_store(r2, (vint4*)(out + base + 8));
        __builtin_nontemporal_store(r3, (vint4*)(out + base + 12));
    } else {
        for (int j = base; j < n; ++j)
            out[j] = query_one_branchy((uint32_t)vals[j], bits);
    }
}

// ---------- fallback path (small ws): global-atomic insert + plain query ----------
__global__ void zero_bits_kernel(vull2* __restrict__ bits, int n2) {
    int i = blockIdx.x * blockDim.x + threadIdx.x;
    if (i < n2) { vull2 z = {0ull, 0ull}; __builtin_nontemporal_store(z, &bits[i]); }
}

__device__ __forceinline__ void insert_one_atomic(uint32_t v,
                                                  unsigned long long* __restrict__ bits) {
    uint32_t p = (v * PRIME) & BIT_MASK;
    uint32_t w = p >> 6, s = p & 63u;
    atomicOr(bits + w, 0x7Full << s);
    if (s > 57u) atomicOr(bits + ((w + 1u) & WORD_MASK), 0x7Full >> (64u - s));
}

__global__ void insert_atomic_kernel(const int* __restrict__ vals, int n,
                                     unsigned long long* __restrict__ bits) {
    int i = blockIdx.x * blockDim.x + threadIdx.x;
    int base = i * 4;
    if (base + 3 < n) {
        vint4 v = __builtin_nontemporal_load((const vint4*)(vals + base));
        insert_one_atomic((uint32_t)v.x, bits);
        insert_one_atomic((uint32_t)v.y, bits);
        insert_one_atomic((uint32_t)v.z, bits);
        insert_one_atomic((uint32_t)v.w, bits);
    } else {
        for (int j = base; j < n; ++j) insert_one_atomic((uint32_t)vals[j], bits);
    }
}

__global__ __launch_bounds__(256) void query_kernel8(
    const int* __restrict__ vals, int n,
    const unsigned long long* __restrict__ bits, int* __restrict__ out)
{
    int t = blockIdx.x * 256 + threadIdx.x;
    int base = t * 8;
    if (base + 7 < n) {
        vint4 v0 = __builtin_nontemporal_load((const vint4*)(vals + base));
        vint4 v1 = __builtin_nontemporal_load((const vint4*)(vals + base + 4));
        vint4 r0, r1;
        #pragma unroll
        for (int j = 0; j < 8; ++j) {
            uint32_t v = (uint32_t)(j < 4 ? v0[j] : v1[j - 4]);
            int r = query_one_branchy(v, bits);
            if (j < 4) r0[j] = r; else r1[j - 4] = r;
        }
        __builtin_nontemporal_store(r0, (vint4*)(out + base));
        __builtin_nontemporal_store(r1, (vint4*)(out + base + 4));
    } else {
        for (int j = base; j < n; ++j)
            out[j] = query_one_branchy((uint32_t)vals[j], bits);
    }
}

extern "C" void kernel_launch(void* const* d_in, const int* in_sizes, int n_in,
                              void* d_out, int out_size, void* d_ws, size_t ws_size,
                              hipStream_t stream) {
    const int* add_values   = (const int*)d_in[0];
    const int* query_values = (const int*)d_in[1];
    const int n_add   = in_sizes[0];   // 4,000,000
    const int n_query = in_sizes[1];   // 8,000,000
    int* out = (int*)d_out;

    uint8_t* ws = (uint8_t*)d_ws;
    unsigned long long* bits = (unsigned long long*)ws;
    unsigned long long* H    = (unsigned long long*)(ws + 16777216);
    uint32_t* lists = (uint32_t*)(ws + 20971520);
    uint32_t* off_t = (uint32_t*)(ws + 38273024);

    if (ws_size >= WS_REQUIRED) {
        scatter_add_kernel<<<BLOCKS_A, 256, 0, stream>>>(
            add_values, n_add, lists, off_t);
        build_bitmap_kernel<<<NBUCKETS, 256, 0, stream>>>(
            lists, off_t, bits, H);
        const int threads = (n_query + 15) / 16;
        query_kernelH16<<<(threads + 255) / 256, 256, 0, stream>>>(
            query_values, n_query, bits, (const uint32_t*)H, out);
    } else {
        const int n2 = NUM_WORDS / 2;
        zero_bits_kernel<<<(n2 + 255) / 256, 256, 0, stream>>>((vull2*)bits, n2);
        const int threads4 = (n_add + 3) / 4;
        insert_atomic_kernel<<<(threads4 + 255) / 256, 256, 0, stream>>>(
            add_values, n_add, bits);
        const int threads = (n_query + 7) / 8;
        query_kernel8<<<(threads + 255) / 256, 256, 0, stream>>>(
            query_values, n_query, bits, out);
    }
}

// Round 13
// 225.491 us; speedup vs baseline: 3.9683x; 1.0914x over previous
//
#include <hip/hip_runtime.h>
#include <stdint.h>

// Bloom filter, 2^27 bits, 7 hashes = 7 CONSECUTIVE bits starting at
//   p = ((uint32)v * 2654435761u) & (2^27 - 1)   (wraps mod 2^27)
// Harness dtypes: integer inputs -> int32; bool output -> int32 (0/1).
//
// R12 post-mortem: 16/thr query doubled VGPR (40->80), halved occupancy
// (52->24%) -> regression; reverted to 8/thr. R9 FETCH decomposition showed
// 67 MB = every fine gather missing to HBM: NT stores (build->bits) + NT
// loads (query->bits) bypass L2/L3 entirely. This round: bits path is fully
// cacheable (plain stores in build, plain fine loads in query); scatter input
// loads also plain so pass 2 hits L3. H stays hot in L2 (122 acc/line vs
// ~1.2 for bits lines). NT retained only for: query input, out stores,
// build list reads (true streams, zero reuse).

#define NUM_BITS_LOG2 27
#define NUM_BITS (1u << NUM_BITS_LOG2)
#define BIT_MASK (NUM_BITS - 1u)
#define NUM_WORDS (NUM_BITS >> 6)             // 2^21 u64 words = 16 MiB
#define WORD_MASK (NUM_WORDS - 1u)
#define PRIME 2654435761u

#define NBUCKETS 512
#define BKT_SHIFT (NUM_BITS_LOG2 - 9)         // 18: region = 2^18 bits
#define REGION_WORDS (1u << (BKT_SHIFT - 6))  // 4096 u64 = 32 KiB
#define H_WORDS_PER_REGION (REGION_WORDS / 4) // 1024 u64 H-words per region
#define BLOCKS_A 256
#define BLOCK_SEG 16896u                      // per-block entry segment (u32)

typedef int vint4 __attribute__((ext_vector_type(4)));
typedef unsigned long long vull2 __attribute__((ext_vector_type(2)));

// ---------------- workspace layout (bytes) ----------------
// [0, 16777216)            bits   u64 x 2^21   (16 MiB)
// [16777216, 20971520)     H      u64 x 2^19   (4 MiB)
// [20971520, 38273024)     lists  u32 x 256*16896
// [38273024, 38798336)     off_t  u32 x 513*256  (off_t[bucket*256+blk])
#define WS_REQUIRED 38798336ull

// ---------- phase A: exact two-pass bucket scatter (no global atomics) ----------
__global__ __launch_bounds__(256) void scatter_add_kernel(
    const int* __restrict__ vals, int n,
    uint32_t* __restrict__ lists, uint32_t* __restrict__ off_t)
{
    __shared__ uint32_t cnt[NBUCKETS];
    __shared__ uint32_t scan[NBUCKETS];
    __shared__ uint32_t off[NBUCKETS + 1];
    __shared__ uint32_t cur[NBUCKETS];
    const int blk = blockIdx.x, tid = threadIdx.x;
    for (int i = tid; i < NBUCKETS; i += 256) cnt[i] = 0;
    __syncthreads();

    const int n4 = n >> 2;
    // ---- pass 1: count (traversal identical to pass 2); plain loads -> L3 ----
    for (int g = blk * 256 + tid; g < n4; g += BLOCKS_A * 256) {
        vint4 v = ((const vint4*)vals)[g];
        #pragma unroll
        for (int j = 0; j < 4; ++j) {
            uint32_t p = ((uint32_t)v[j] * PRIME) & BIT_MASK;
            uint32_t b1 = p >> BKT_SHIFT;
            atomicAdd(&cnt[b1], 1u);
            uint32_t b2 = ((p + 6u) & BIT_MASK) >> BKT_SHIFT;
            if (b2 != b1) atomicAdd(&cnt[b2], 1u);
        }
    }
    for (int i = (n4 << 2) + blk * 256 + tid; i < n; i += BLOCKS_A * 256) {
        uint32_t p = ((uint32_t)vals[i] * PRIME) & BIT_MASK;
        uint32_t b1 = p >> BKT_SHIFT;
        atomicAdd(&cnt[b1], 1u);
        uint32_t b2 = ((p + 6u) & BIT_MASK) >> BKT_SHIFT;
        if (b2 != b1) atomicAdd(&cnt[b2], 1u);
    }
    __syncthreads();

    // ---- Hillis-Steele inclusive scan over 512 bins (each thread owns 2) ----
    scan[tid] = cnt[tid];
    scan[tid + 256] = cnt[tid + 256];
    __syncthreads();
    for (uint32_t d = 1; d < NBUCKETS; d <<= 1) {
        uint32_t i0 = tid, i1 = tid + 256;
        uint32_t v0 = (i0 >= d) ? scan[i0 - d] : 0u;
        uint32_t v1 = (i1 >= d) ? scan[i1 - d] : 0u;
        __syncthreads();
        scan[i0] += v0;
        scan[i1] += v1;
        __syncthreads();
    }
    if (tid == 0) off[0] = 0;
    off[tid + 1] = scan[tid];
    off[tid + 257] = scan[tid + 256];
    __syncthreads();
    cur[tid] = off[tid];
    cur[tid + 256] = off[tid + 256];
    __syncthreads();

    // ---- pass 2: exact scatter (input now L3-hot) ----
    const uint32_t seg = (uint32_t)blk * BLOCK_SEG;
    for (int g = blk * 256 + tid; g < n4; g += BLOCKS_A * 256) {
        vint4 v = ((const vint4*)vals)[g];
        #pragma unroll
        for (int j = 0; j < 4; ++j) {
            uint32_t p = ((uint32_t)v[j] * PRIME) & BIT_MASK;
            uint32_t b1 = p >> BKT_SHIFT;
            uint32_t s = atomicAdd(&cur[b1], 1u);
            if (s < BLOCK_SEG) lists[seg + s] = p;        // clamp: unreachable for this input
            uint32_t b2 = ((p + 6u) & BIT_MASK) >> BKT_SHIFT;
            if (b2 != b1) {
                uint32_t s2 = atomicAdd(&cur[b2], 1u);
                if (s2 < BLOCK_SEG) lists[seg + s2] = p;
            }
        }
    }
    for (int i = (n4 << 2) + blk * 256 + tid; i < n; i += BLOCKS_A * 256) {
        uint32_t p = ((uint32_t)vals[i] * PRIME) & BIT_MASK;
        uint32_t b1 = p >> BKT_SHIFT;
        uint32_t s = atomicAdd(&cur[b1], 1u);
        if (s < BLOCK_SEG) lists[seg + s] = p;
        uint32_t b2 = ((p + 6u) & BIT_MASK) >> BKT_SHIFT;
        if (b2 != b1) {
            uint32_t s2 = atomicAdd(&cur[b2], 1u);
            if (s2 < BLOCK_SEG) lists[seg + s2] = p;
        }
    }
    __syncthreads();
    // off_t transposed: build block b reads off_t[b*256 + tid] coalesced
    for (int i = tid; i < NBUCKETS + 1; i += 256)
        off_t[(uint32_t)i * BLOCKS_A + blk] = off[i];
}

// ---------- phase B: build region bitmap in LDS, emit bits + H ----------
__device__ __forceinline__ void set_window(unsigned long long* bm, uint32_t p, uint32_t b) {
    int d = (int)((p - (b << BKT_SHIFT)) & BIT_MASK);
    if (d >= (1 << 26)) d -= (1 << 27);                 // dup from prev region / wrap
    if (d < -6 || d >= (1 << BKT_SHIFT)) return;        // safety guard
    if (d < 0) {
        atomicOr(&bm[0], 0x7Full >> (uint32_t)(-d));
    } else {
        uint32_t w = (uint32_t)d >> 6, s = (uint32_t)d & 63u;
        atomicOr(&bm[w], 0x7Full << s);
        if (s > 57u) atomicOr(&bm[w + 1], 0x7Full >> (64u - s));  // slack word absorbs
    }
}

// 16 nibble-AND bits of one u64 fine word, compacted to low 16 bits
__device__ __forceinline__ unsigned long long nib16(unsigned long long a) {
    unsigned long long t = a & (a >> 1);
    unsigned long long u = t & (t >> 2);                // bit 4k = AND of bits 4k..4k+3
    u &= 0x1111111111111111ull;
    u |= u >> 3;  u &= 0x0303030303030303ull;
    u |= u >> 6;  u &= 0x000F000F000F000Full;
    u |= u >> 12; u &= 0x000000FF000000FFull;
    u |= u >> 24; return u & 0xFFFFull;
}

__global__ __launch_bounds__(256) void build_bitmap_kernel(
    const uint32_t* __restrict__ lists, const uint32_t* __restrict__ off_t,
    unsigned long long* __restrict__ bits, unsigned long long* __restrict__ H)
{
    __shared__ unsigned long long bm[REGION_WORDS + 1];
    __shared__ uint32_t o0s[BLOCKS_A];
    __shared__ uint32_t c_s[BLOCKS_A];
    const uint32_t b = blockIdx.x, tid = threadIdx.x;
    for (uint32_t i = tid; i < REGION_WORDS + 1; i += 256) bm[i] = 0ull;
    for (uint32_t a = tid; a < BLOCKS_A; a += 256) {               // coalesced
        uint32_t o0 = min(off_t[b * BLOCKS_A + a], BLOCK_SEG);
        uint32_t o1 = min(off_t[(b + 1) * BLOCKS_A + a], BLOCK_SEG);
        o0s[a] = o0;
        c_s[a] = (o1 > o0) ? (o1 - o0) : 0u;
    }
    __syncthreads();

    // wave-cooperative: wave w walks source blocks w, w+4, ...; lanes coalesced
    const uint32_t wave = tid >> 6, lane = tid & 63u;
    for (uint32_t a = wave; a < BLOCKS_A; a += 4) {
        uint32_t c = c_s[a];
        uint32_t base = a * BLOCK_SEG + o0s[a];
        for (uint32_t k = lane; k < c; k += 64)
            set_window(bm, __builtin_nontemporal_load(&lists[base + k]), b);
    }
    __syncthreads();
    // PLAIN stores: bits must land in L2/L3 so query fine gathers hit cache
    const uint32_t out_base = b * REGION_WORDS;
    for (uint32_t i = tid; i < REGION_WORDS; i += 256)
        bits[out_base + i] = bm[i];
    const uint32_t h_base = b * H_WORDS_PER_REGION;
    for (uint32_t i = tid; i < H_WORDS_PER_REGION; i += 256) {
        unsigned long long hw = nib16(bm[i * 4])
                              | (nib16(bm[i * 4 + 1]) << 16)
                              | (nib16(bm[i * 4 + 2]) << 32)
                              | (nib16(bm[i * 4 + 3]) << 48);
        H[h_base + i] = hw;                 // temporal store: H wants to live in L2
    }
}

// ---------- query: 8/thread; H pre-filter, cacheable fine gathers ----------
__device__ __forceinline__ int query_one_branchy(uint32_t v,
                                                 const unsigned long long* __restrict__ bits) {
    uint32_t p = (v * PRIME) & BIT_MASK;
    uint32_t w = p >> 6, s = p & 63u;
    unsigned long long lo = bits[w];
    unsigned long long win;
    if (s <= 57u) win = lo >> s;
    else win = (lo >> s) | (bits[(w + 1u) & WORD_MASK] << (64u - s));
    return ((win & 0x7Full) == 0x7Full) ? 1 : 0;
}

__global__ __launch_bounds__(256) void query_kernelH(
    const int* __restrict__ vals, int n,
    const unsigned long long* __restrict__ bits,
    const uint32_t* __restrict__ H32, int* __restrict__ out)
{
    int t = blockIdx.x * 256 + threadIdx.x;
    int base = t * 8;
    if (base + 7 < n) {
        vint4 v0 = __builtin_nontemporal_load((const vint4*)(vals + base));
        vint4 v1 = __builtin_nontemporal_load((const vint4*)(vals + base + 4));
        uint32_t p[8], pass[8];
        #pragma unroll
        for (int j = 0; j < 4; ++j) {
            p[j]     = ((uint32_t)v0[j] * PRIME) & BIT_MASK;
            p[j + 4] = ((uint32_t)v1[j] * PRIME) & BIT_MASK;
        }
        #pragma unroll
        for (int j = 0; j < 8; ++j) {           // 8 independent L2-hit H probes
            uint32_t m = ((p[j] + 3u) & BIT_MASK) >> 2;
            pass[j] = (H32[m >> 5] >> (m & 31u)) & 1u;
        }
        unsigned long long lo[8], hi[8];
        uint32_t w[8], s[8];
        #pragma unroll
        for (int j = 0; j < 8; ++j) {           // masked fine gathers (~13% lanes), cacheable
            w[j] = p[j] >> 6; s[j] = p[j] & 63u;
            lo[j] = 0ull; hi[j] = 0ull;
            if (pass[j]) lo[j] = bits[w[j]];
        }
        #pragma unroll
        for (int j = 0; j < 8; ++j) {           // masked hi gathers (~1.1% lanes)
            if (pass[j] && s[j] > 57u)
                hi[j] = bits[(w[j] + 1u) & WORD_MASK];
        }
        vint4 r0, r1;
        #pragma unroll
        for (int j = 0; j < 8; ++j) {
            unsigned long long win = (lo[j] >> s[j]) | ((hi[j] << 1) << (63u - s[j]));
            int r = ((win & 0x7Full) == 0x7Full) ? 1 : 0;
            if (j < 4) r0[j] = r; else r1[j - 4] = r;
        }
        __builtin_nontemporal_store(r0, (vint4*)(out + base));
        __builtin_nontemporal_store(r1, (vint4*)(out + base + 4));
    } else {
        for (int j = base; j < n; ++j)
            out[j] = query_one_branchy((uint32_t)vals[j], bits);
    }
}

// ---------- fallback path (small ws): global-atomic insert + plain query ----------
__global__ void zero_bits_kernel(vull2* __restrict__ bits, int n2) {
    int i = blockIdx.x * blockDim.x + threadIdx.x;
    if (i < n2) { vull2 z = {0ull, 0ull}; __builtin_nontemporal_store(z, &bits[i]); }
}

__device__ __forceinline__ void insert_one_atomic(uint32_t v,
                                                  unsigned long long* __restrict__ bits) {
    uint32_t p = (v * PRIME) & BIT_MASK;
    uint32_t w = p >> 6, s = p & 63u;
    atomicOr(bits + w, 0x7Full << s);
    if (s > 57u) atomicOr(bits + ((w + 1u) & WORD_MASK), 0x7Full >> (64u - s));
}

__global__ void insert_atomic_kernel(const int* __restrict__ vals, int n,
                                     unsigned long long* __restrict__ bits) {
    int i = blockIdx.x * blockDim.x + threadIdx.x;
    int base = i * 4;
    if (base + 3 < n) {
        vint4 v = __builtin_nontemporal_load((const vint4*)(vals + base));
        insert_one_atomic((uint32_t)v.x, bits);
        insert_one_atomic((uint32_t)v.y, bits);
        insert_one_atomic((uint32_t)v.z, bits);
        insert_one_atomic((uint32_t)v.w, bits);
    } else {
        for (int j = base; j < n; ++j) insert_one_atomic((uint32_t)vals[j], bits);
    }
}

__global__ __launch_bounds__(256) void query_kernel8(
    const int* __restrict__ vals, int n,
    const unsigned long long* __restrict__ bits, int* __restrict__ out)
{
    int t = blockIdx.x * 256 + threadIdx.x;
    int base = t * 8;
    if (base + 7 < n) {
        vint4 v0 = __builtin_nontemporal_load((const vint4*)(vals + base));
        vint4 v1 = __builtin_nontemporal_load((const vint4*)(vals + base + 4));
        vint4 r0, r1;
        #pragma unroll
        for (int j = 0; j < 8; ++j) {
            uint32_t v = (uint32_t)(j < 4 ? v0[j] : v1[j - 4]);
            int r = query_one_branchy(v, bits);
            if (j < 4) r0[j] = r; else r1[j - 4] = r;
        }
        __builtin_nontemporal_store(r0, (vint4*)(out + base));
        __builtin_nontemporal_store(r1, (vint4*)(out + base + 4));
    } else {
        for (int j = base; j < n; ++j)
            out[j] = query_one_branchy((uint32_t)vals[j], bits);
    }
}

extern "C" void kernel_launch(void* const* d_in, const int* in_sizes, int n_in,
                              void* d_out, int out_size, void* d_ws, size_t ws_size,
                              hipStream_t stream) {
    const int* add_values   = (const int*)d_in[0];
    const int* query_values = (const int*)d_in[1];
    const int n_add   = in_sizes[0];   // 4,000,000
    const int n_query = in_sizes[1];   // 8,000,000
    int* out = (int*)d_out;

    uint8_t* ws = (uint8_t*)d_ws;
    unsigned long long* bits = (unsigned long long*)ws;
    unsigned long long* H    = (unsigned long long*)(ws + 16777216);
    uint32_t* lists = (uint32_t*)(ws + 20971520);
    uint32_t* off_t = (uint32_t*)(ws + 38273024);

    if (ws_size >= WS_REQUIRED) {
        scatter_add_kernel<<<BLOCKS_A, 256, 0, stream>>>(
            add_values, n_add, lists, off_t);
        build_bitmap_kernel<<<NBUCKETS, 256, 0, stream>>>(
            lists, off_t, bits, H);
        const int threads = (n_query + 7) / 8;
        query_kernelH<<<(threads + 255) / 256, 256, 0, stream>>>(
            query_values, n_query, bits, (const uint32_t*)H, out);
    } else {
        const int n2 = NUM_WORDS / 2;
        zero_bits_kernel<<<(n2 + 255) / 256, 256, 0, stream>>>((vull2*)bits, n2);
        const int threads4 = (n_add + 3) / 4;
        insert_atomic_kernel<<<(threads4 + 255) / 256, 256, 0, stream>>>(
            add_values, n_add, bits);
        const int threads = (n_query + 7) / 8;
        query_kernel8<<<(threads + 255) / 256, 256, 0, stream>>>(
            query_values, n_query, bits, out);
    }
}